// Round 5
// baseline (551.009 us; speedup 1.0000x reference)
//
#include <hip/hip_runtime.h>
#include <math.h>

#define B_ 32
#define H_ 32
#define HKV_ 8
#define G_ 4
#define D_ 128
#define BS_ 16
#define MAXNB_ 256
#define NPAGES_ 4096
#define NSLOTS_ (NPAGES_ * BS_)
#define PGSZ_ (BS_ * HKV_ * D_)   // floats per cache page-block
#define NSPLIT_ 16                // p_per <= 16 always
#define OVW_ 10                   // padded u32 words per batch in ovr bitmap
// SCALE * log2(e): work in exp2 domain (v_exp_f32 is the hw op)
#define SC_ (0.08838834764831845f * 1.4426950408889634f)
#define NEG_ -1e30f

// ---------------- kernel 1: build virtual-scatter structures (NO cache mutation) --
// map [65536]   : slot -> batch_idx+1  (rare-path lookup)
// pagemask[4096]: page -> token bitmask (build-time only)
// ovr [B][OVW_] : per-batch bitmap over block-table positions 0..255 — bit pos
//                 set iff block_tables[b][pos] names a page holding an
//                 overridden slot. Scalar-register check per page in attn.
__global__ void build_slot_map(const int* __restrict__ slot_mapping,
                               const int* __restrict__ block_tables,
                               unsigned char* __restrict__ map,
                               unsigned int* __restrict__ pagemask,
                               unsigned int* __restrict__ ovr) {
  const int tid = threadIdx.x;   // one workgroup, 256 threads
  uint4* m4 = (uint4*)map;
#pragma unroll
  for (int i = 0; i < NSLOTS_ / 16 / 256; ++i)      // 64 KiB
    m4[tid + i * 256] = make_uint4(0u, 0u, 0u, 0u);
  uint4* p4 = (uint4*)pagemask;
#pragma unroll
  for (int i = 0; i < NPAGES_ * 4 / 16 / 256; ++i)  // 16 KiB
    p4[tid + i * 256] = make_uint4(0u, 0u, 0u, 0u);
  for (int i = tid; i < B_ * OVW_; i += 256) ovr[i] = 0u;
  __syncthreads();
  if (tid == 0) {
    // serial ascending writes -> deterministic last-wins on duplicate slots
#pragma unroll
    for (int j = 0; j < B_; ++j) {
      int s = slot_mapping[j];
      map[s] = (unsigned char)(j + 1);
      pagemask[s >> 4] |= (1u << (s & 15));
    }
  }
  __syncthreads();
  // scan all (b, pos) block-table entries against the affected-page set
  for (int e = tid; e < B_ * MAXNB_; e += 256) {
    int pgid = block_tables[e];
    if (pgid >= 0 && pgid < NPAGES_ && pagemask[pgid] != 0u) {
      int bb = e >> 8;           // MAXNB_ == 256
      int pos = e & 255;
      atomicOr(&ovr[bb * OVW_ + (pos >> 5)], 1u << (pos & 31));
    }
  }
}

// ---------------- kernel 2: flash-decode split-K attention, ONE WAVE per block ----
// Grid: B*HKV*NSPLIT_ blocks of 64 threads. Lane: tg = lane>>4 (token subgroup),
// c = lane&15 (8-float d-chunk). Page = 4 sub-steps of 4 tokens, held in 4
// register slots; slot X reloads for page pg+1 right after page pg consumes it.
// No LDS, no barriers anywhere: dot-reduce and final merge are pure shfl.
// launch_bounds(64,2): VGPR cap 256 -> guaranteed no scratch spill.
__global__ __launch_bounds__(64, 2) void attn_split(
    const float* __restrict__ q,
    const float* __restrict__ k_new,        // [B][HKV][D] new-token k
    const float* __restrict__ v_new,        // [B][HKV][D] new-token v
    const float* __restrict__ k_cache,
    const float* __restrict__ v_cache,
    const int* __restrict__ block_tables,
    const int* __restrict__ context_lens,
    const unsigned char* __restrict__ map,
    const unsigned int* __restrict__ ovr,
    float* __restrict__ O_part,   // [B][HKV][G][NSPLIT_][D]
    float* __restrict__ M_part,   // [B][HKV][G][NSPLIT_]
    float* __restrict__ L_part)   // [B][HKV][G][NSPLIT_]
{
  const int lane = threadIdx.x;
  const int tg = lane >> 4;         // token subgroup 0..3
  const int c  = lane & 15;         // 8-float d-chunk

  const int s  = blockIdx.x % NSPLIT_;
  const int bk = blockIdx.x / NSPLIT_;
  const int kv = bk % HKV_;
  const int b  = bk / HKV_;

  // q fragment for 4 group heads, pre-scaled into exp2 domain
  float qr[G_][8];
#pragma unroll
  for (int g = 0; g < G_; ++g) {
    const float* qp = q + ((size_t)(b * H_ + kv * G_ + g)) * D_ + c * 8;
    float4 a0 = *(const float4*)qp;
    float4 a1 = *(const float4*)(qp + 4);
    qr[g][0] = a0.x * SC_; qr[g][1] = a0.y * SC_;
    qr[g][2] = a0.z * SC_; qr[g][3] = a0.w * SC_;
    qr[g][4] = a1.x * SC_; qr[g][5] = a1.y * SC_;
    qr[g][6] = a1.z * SC_; qr[g][7] = a1.w * SC_;
  }

  float m2[G_], l[G_], o[G_][8];
#pragma unroll
  for (int g = 0; g < G_; ++g) {
    m2[g] = NEG_; l[g] = 0.f;
#pragma unroll
    for (int j = 0; j < 8; ++j) o[g][j] = 0.f;
  }

  const int ctx = context_lens[b];
  const int pages_total = (ctx + BS_ - 1) / BS_;
  const int p_per = (pages_total + NSPLIT_ - 1) / NSPLIT_;   // <= 16
  const int p0 = s * p_per;
  const int p1 = min(p0 + p_per, pages_total);
  const int bt_base = b * MAXNB_;

  // lane's float offset inside a 4-token strip of a page
  const int loff = tg * (HKV_ * D_) + kv * D_ + c * 8;

  // override-bit window: bits [p0, p0+p_per) of ovr[b]  (p_per <= 16)
  unsigned long long dwr;
  {
    const unsigned int* ow = ovr + b * OVW_;
    const int i0 = p0 >> 5, s0 = p0 & 31;
    unsigned long long lo = ow[i0], hi = ow[i0 + 1];
    dwr = ((hi << 32) | lo) >> s0;
  }

  // 4 register slots: slot X = tokens [4X, 4X+4) of the current page
  float4 kk0[4], kk1[4], vv0[4], vv1[4];
  int blkP = 0, blkN = 0;

  if (p0 < p1) {
    blkP = block_tables[bt_base + p0];                 // uniform -> s_load
    const int nb = blkP < 0 ? 0 : blkP;
    const float* kb = k_cache + (size_t)nb * PGSZ_ + loff;
    const float* vb = v_cache + (size_t)nb * PGSZ_ + loff;
#pragma unroll
    for (int X = 0; X < 4; ++X) {
      const float* kp = kb + X * (4 * HKV_ * D_);
      const float* vp = vb + X * (4 * HKV_ * D_);
      kk0[X] = *(const float4*)kp; kk1[X] = *(const float4*)(kp + 4);
      vv0[X] = *(const float4*)vp; vv1[X] = *(const float4*)(vp + 4);
    }
    blkN = (p0 + 1 < p1) ? block_tables[bt_base + p0 + 1] : 0;
  }

  for (int pg = p0; pg < p1; ++pg) {
    // rare virtual-scatter override for this page (uniform bit)
    if (dwr & 1ull) {
      const int bc0 = blkP < 0 ? 0 : blkP;
#pragma unroll
      for (int X = 0; X < 4; ++X) {
        const int mj = map[bc0 * BS_ + X * 4 + tg];
        if (mj != 0) {
          const int j = mj - 1;
          const float* kp = k_new + ((size_t)(j * HKV_ + kv)) * D_ + c * 8;
          const float* vp = v_new + ((size_t)(j * HKV_ + kv)) * D_ + c * 8;
          kk0[X] = *(const float4*)kp; kk1[X] = *(const float4*)(kp + 4);
          vv0[X] = *(const float4*)vp; vv1[X] = *(const float4*)(vp + 4);
        }
      }
    }

    const bool more = (pg + 1 < p1);
    const int nb = blkN < 0 ? 0 : blkN;
    const float* nkb = k_cache + (size_t)nb * PGSZ_ + loff;
    const float* nvb = v_cache + (size_t)nb * PGSZ_ + loff;

#pragma unroll
    for (int X = 0; X < 4; ++X) {
      float dt[G_];
#pragma unroll
      for (int g = 0; g < G_; ++g) {
        dt[g] = qr[g][0] * kk0[X].x + qr[g][1] * kk0[X].y
              + qr[g][2] * kk0[X].z + qr[g][3] * kk0[X].w
              + qr[g][4] * kk1[X].x + qr[g][5] * kk1[X].y
              + qr[g][6] * kk1[X].z + qr[g][7] * kk1[X].w;
      }
      // K(X) consumed -> stream in slot X of page pg+1
      if (more) {
        const float* kp = nkb + X * (4 * HKV_ * D_);
        kk0[X] = *(const float4*)kp; kk1[X] = *(const float4*)(kp + 4);
      }
      // reduce partial dots across the 16 c-lanes sharing a token
#pragma unroll
      for (int off = 1; off < 16; off <<= 1) {
#pragma unroll
        for (int g = 0; g < G_; ++g) dt[g] += __shfl_xor(dt[g], off, 16);
      }
      const int pos = pg * BS_ + X * 4 + tg;
      if ((pos < ctx) && (blkP >= 0)) {
#pragma unroll
        for (int g = 0; g < G_; ++g) {
          float t2 = dt[g];
          float mn = fmaxf(m2[g], t2);
          float al = exp2f(m2[g] - mn);
          float p  = exp2f(t2 - mn);
          l[g] = l[g] * al + p;
          m2[g] = mn;
          o[g][0] = o[g][0] * al + p * vv0[X].x;
          o[g][1] = o[g][1] * al + p * vv0[X].y;
          o[g][2] = o[g][2] * al + p * vv0[X].z;
          o[g][3] = o[g][3] * al + p * vv0[X].w;
          o[g][4] = o[g][4] * al + p * vv1[X].x;
          o[g][5] = o[g][5] * al + p * vv1[X].y;
          o[g][6] = o[g][6] * al + p * vv1[X].z;
          o[g][7] = o[g][7] * al + p * vv1[X].w;
        }
      }
      // V(X) consumed -> stream in slot X of page pg+1
      if (more) {
        const float* vp = nvb + X * (4 * HKV_ * D_);
        vv0[X] = *(const float4*)vp; vv1[X] = *(const float4*)(vp + 4);
      }
    }

    blkP = blkN;
    blkN = (pg + 2 < p1) ? block_tables[bt_base + pg + 2] : 0;
    dwr >>= 1;
  }

  // ---- merge the 4 token subgroups in-wave (lanes ^16, ^32) ----
#pragma unroll
  for (int off = 16; off < 64; off <<= 1) {
#pragma unroll
    for (int g = 0; g < G_; ++g) {
      float mo = __shfl_xor(m2[g], off, 64);
      float lo = __shfl_xor(l[g], off, 64);
      float mn = fmaxf(m2[g], mo);
      float f1 = exp2f(m2[g] - mn);
      float f2 = exp2f(mo - mn);
      l[g] = f1 * l[g] + f2 * lo;
      m2[g] = mn;
#pragma unroll
      for (int j = 0; j < 8; ++j)
        o[g][j] = f1 * o[g][j] + f2 * __shfl_xor(o[g][j], off, 64);
    }
  }

  // ---- write this split's partial (lanes 0..15 hold the merged result) ----
  if (lane < 16) {
#pragma unroll
    for (int g = 0; g < G_; ++g) {
      const size_t pi = ((size_t)((b * HKV_ + kv) * G_ + g) * NSPLIT_ + s);
      float* dst = O_part + pi * D_ + c * 8;
      *(float4*)dst       = make_float4(o[g][0], o[g][1], o[g][2], o[g][3]);
      *(float4*)(dst + 4) = make_float4(o[g][4], o[g][5], o[g][6], o[g][7]);
      if (lane == 0) { M_part[pi] = m2[g]; L_part[pi] = l[g]; }
    }
  }
}

// ---------------- kernel 3: combine splits ----------------
__global__ void combine_splits(const float* __restrict__ O_part,
                               const float* __restrict__ M_part,
                               const float* __restrict__ L_part,
                               const int* __restrict__ context_lens,
                               float* __restrict__ out) {
  const int blk = blockIdx.x;      // b*H + h  (h = kv*4+g)
  const int b = blk >> 5;
  const int d = threadIdx.x;       // 128 threads
  const int ctx = context_lens[b];
  float r = 0.f;
  if (ctx > 0) {
    const size_t base = (size_t)blk * NSPLIT_;
    float M = NEG_;
#pragma unroll
    for (int s = 0; s < NSPLIT_; ++s) M = fmaxf(M, M_part[base + s]);
    float den = 0.f, acc = 0.f;
#pragma unroll
    for (int s = 0; s < NSPLIT_; ++s) {
      float f = exp2f(M_part[base + s] - M);
      den += f * L_part[base + s];
      acc += f * O_part[(base + s) * D_ + d];
    }
    r = den > 0.f ? acc / den : 0.f;
  }
  out[(size_t)blk * D_ + d] = r;
}

extern "C" void kernel_launch(void* const* d_in, const int* in_sizes, int n_in,
                              void* d_out, int out_size, void* d_ws, size_t ws_size,
                              hipStream_t stream) {
  const float* q = (const float*)d_in[0];
  const float* k = (const float*)d_in[1];
  const float* v = (const float*)d_in[2];
  const float* k_cache = (const float*)d_in[3];   // read-only: no restore cost
  const float* v_cache = (const float*)d_in[4];
  const int* slot_mapping = (const int*)d_in[5];
  const int* block_tables = (const int*)d_in[6];
  const int* context_lens = (const int*)d_in[7];
  float* out = (float*)d_out;

  // ws layout: [64K map][16K pagemask][2K ovr][O_part][M_part][L_part]
  const size_t map_bytes = NSLOTS_;
  const size_t pmask_bytes = NPAGES_ * sizeof(unsigned int);
  const size_t ovr_bytes = 2048;     // 32*OVW_*4 = 1280, padded
  unsigned char* map = (unsigned char*)d_ws;
  unsigned int* pagemask = (unsigned int*)((char*)d_ws + map_bytes);
  unsigned int* ovr = (unsigned int*)((char*)d_ws + map_bytes + pmask_bytes);

  float* O_part = (float*)((char*)d_ws + map_bytes + pmask_bytes + ovr_bytes);
  float* M_part = O_part + (size_t)B_ * HKV_ * G_ * NSPLIT_ * D_;
  float* L_part = M_part + (size_t)B_ * HKV_ * G_ * NSPLIT_;

  build_slot_map<<<1, 256, 0, stream>>>(slot_mapping, block_tables,
                                        map, pagemask, ovr);
  attn_split<<<B_ * HKV_ * NSPLIT_, 64, 0, stream>>>(
      q, k, v, k_cache, v_cache, block_tables, context_lens, map, ovr,
      O_part, M_part, L_part);
  combine_splits<<<B_ * H_, D_, 0, stream>>>(O_part, M_part, L_part,
                                             context_lens, out);
}